// Round 3
// baseline (687.522 us; speedup 1.0000x reference)
//
#include <hip/hip_runtime.h>
#include <hip/hip_bf16.h>

#define NB 16384
#define NZ 128
#define NH 512
#define NHID 512
#define NT 32

typedef __attribute__((ext_vector_type(8))) short short8;
typedef __attribute__((ext_vector_type(4))) short short4v;
typedef __attribute__((ext_vector_type(4))) float f32x4;
typedef __attribute__((ext_vector_type(2))) long long2v;

__device__ __forceinline__ short f2bf(float x) {
    union { __hip_bfloat16 h; short s; } u; u.h = __float2bfloat16(x); return u.s;
}
__device__ __forceinline__ float bf2f(short s) {
    union { unsigned int u; float f; } v; v.u = ((unsigned int)(unsigned short)s) << 16; return v.f;
}

// ---------------------------------------------------------------------------
// Prologue pack:
//  w1aT  bf16 A-frags [ht(32)][kt(4)]   (128 frags x 1KB)
//  w2T8  fp8  A-frags [kt2(16)][jt(8)]  (128 frags x 512B)
//  w1bT  bf16 A-frags [ht(32)][kt(16)]  (512 frags x 1KB)
// A-frag 16x16x32: lane l holds A[m=l&15][k=(l>>4)*8+j], j=0..7.
// ---------------------------------------------------------------------------
__global__ __launch_bounds__(64) void pack_weights(const float* __restrict__ W1,
                                                   const float* __restrict__ W2,
                                                   short* __restrict__ w1aT,
                                                   long* __restrict__ w2T8,
                                                   short* __restrict__ w1bT) {
    int f = blockIdx.x;
    int l = threadIdx.x;
    int quad = l >> 4, m = l & 15;
    if (f < 128) {                       // W1a^T : A[h][k] = W1[k][h], k<128
        int ht = f >> 2, kt = f & 3;
        short8 o;
#pragma unroll
        for (int j = 0; j < 8; ++j)
            o[j] = f2bf(W1[(size_t)(kt * 32 + quad * 8 + j) * NH + ht * 16 + m]);
        *(short8*)(w1aT + ((size_t)f * 64 + l) * 8) = o;
    } else if (f < 256) {                // W2^T fp8 : A[j][k=h] = W2[h][j]
        int g = f - 128; int kt2 = g >> 3, jt = g & 7;
        float v[8];
#pragma unroll
        for (int j = 0; j < 8; ++j)
            v[j] = W2[(size_t)(kt2 * 32 + quad * 8 + j) * NZ + jt * 16 + m];
        int lo = __builtin_amdgcn_cvt_pk_fp8_f32(v[0], v[1], 0, false);
        lo = __builtin_amdgcn_cvt_pk_fp8_f32(v[2], v[3], lo, true);
        int hi = __builtin_amdgcn_cvt_pk_fp8_f32(v[4], v[5], 0, false);
        hi = __builtin_amdgcn_cvt_pk_fp8_f32(v[6], v[7], hi, true);
        long pv = ((long)(unsigned int)hi << 32) | (unsigned int)lo;
        w2T8[(size_t)g * 64 + l] = pv;
    } else {                             // W1b^T : A[h][k] = W1[128+k][h]
        int g = f - 256; int ht = g >> 4, kt = g & 15;
        short8 o;
#pragma unroll
        for (int j = 0; j < 8; ++j)
            o[j] = f2bf(W1[(size_t)(128 + kt * 32 + quad * 8 + j) * NH + ht * 16 + m]);
        *(short8*)(w1bT + ((size_t)g * 64 + l) * 8) = o;
    }
}

// ---------------------------------------------------------------------------
// Main: 256 blocks x 512 thr (8 waves), 64 rows/block.
// OCCUPANCY NOTE (rounds 1-2 post-mortem): arch VGPR (116-128) + AGPR acc
// exceeds 128/wave total -> hard 2 waves/SIMD with register-resident weights.
// Grid games don't change that (round 2: 512 blocks, occupancy still 22.6%).
// So: minimize stall cycles per step at fixed occupancy instead.
//   (a) Elementwise runs in GEMM2's OUTPUT register layout (lane holds
//       u[row=rs*16+m][col=16w+quad*4+i]) -> u never goes through LDS,
//       barrier C deleted (3 -> 2 barriers/step). z and eps adopt the same
//       layout; z-publish reuses the (harness-verified) ubw_off swizzle.
//   (b) hid LDS layout stores kt2-PAIRS contiguously: GEMM2 = 16 ds_read_b128
//       (was 32 b64 at 8-way conflict). 16B-granule XOR-swizzle by m spans
//       all 32 banks -> conflict-optimal reads and near-optimal writes.
//   (c) eps prefetch issued at GEMM1 start; barriers are raw s_barrier with
//       lgkmcnt(0)-only waits so the prefetch survives both barriers.
// LDS 49KB: zu[4][16][256B] bf16 z | hid[4][16][512B] fp8 | sconst[32][8]f32.
// ---------------------------------------------------------------------------
__global__ __launch_bounds__(512, 2) void diffusion_main(
    const float* __restrict__ eps0, const float* __restrict__ eps,
    const float* __restrict__ beta, const float* __restrict__ sigma0,
    const float* __restrict__ ctx, const float* __restrict__ b1,
    const float* __restrict__ b2, const float* __restrict__ t_emb,
    const float* __restrict__ target_mu,
    const short* __restrict__ w1aT, const short* __restrict__ w1bT,
    const long* __restrict__ w2T8, float* __restrict__ out)
{
    __shared__ alignas(16) char lds[50176];
    char* zu = lds;                      // 16 KB: [rs(4)][m(16)][256B]
    char* hidb = lds + 16384;            // 32 KB: [rs(4)][m(16)][512B]
    float* scb = (float*)(lds + 49152);  // 1 KB step constants
    const int w = threadIdx.x >> 6;
    const int lane = threadIdx.x & 63;
    const int quad = lane >> 4;
    const int m = lane & 15;
    const int swz = m & 7;
    const int rowbase = blockIdx.x * 64;
    const int jcol = w * 16 + quad * 4;  // this lane's elementwise z-columns
    const float dt = 1.0f / 32.0f;
    const float s0 = sigma0[0];
    const float logs0 = logf(s0);
    const f32x4 zero = {0.f, 0.f, 0.f, 0.f};

    // LDS address bases (per-lane constants)
    const int zu_base = m * 256 + ((quad ^ swz) << 4);   // GEMM1 z read: ^ (kt<<6), +rs*4096
    const int zw_off  = m * 256 + ((((w << 1) + (quad >> 1)) ^ swz) << 4)
                      + ((quad & 1) << 3);               // EW z write (u-layout), +rs*4096
    const int hw_base = m * 512 + ((quad & 1) << 2);     // hid write: +Gc, +rs*8192
    const int hr_base = m * 512;                         // hid read: +((kp*4+quad)^m)<<4, +rs*8192

    // step constants (computed once)
    if (threadIdx.x < 32) {
        int t = threadIdx.x;
        float bfv = beta[t];
        float bbv = beta[(t + 31) & 31];
        float sf = sqrtf(2.f * bfv * dt) * s0;
        float sb = sqrtf(2.f * bbv * dt) * s0;
        scb[t * 8 + 0] = bfv;
        scb[t * 8 + 1] = sf;
        scb[t * 8 + 2] = 1.f / sb;
        scb[t * 8 + 3] = 0.5f * (logf(bfv) - logf(bbv));
        scb[t * 8 + 4] = 1.f - bbv * dt;
    }

    // ---- prologue: cbr[c][rs] = (ctx @ W1b + b1), this wave's 4 h-tiles ----
    f32x4 pacc[4][4];
#pragma unroll
    for (int c = 0; c < 4; ++c)
#pragma unroll
        for (int rs = 0; rs < 4; ++rs) pacc[c][rs] = zero;
#pragma unroll 4
    for (int kt = 0; kt < 16; ++kt) {
        short8 cf[4];
#pragma unroll
        for (int rs = 0; rs < 4; ++rs) {
            const float* cp = ctx + (size_t)(rowbase + rs * 16 + m) * NH + kt * 32 + quad * 8;
            f32x4 a = *(const f32x4*)cp;
            f32x4 b = *(const f32x4*)(cp + 4);
            short8 tt;
#pragma unroll
            for (int j = 0; j < 4; ++j) { tt[j] = f2bf(a[j]); tt[4 + j] = f2bf(b[j]); }
            cf[rs] = tt;
        }
#pragma unroll
        for (int c = 0; c < 4; ++c) {
            short8 af = *(const short8*)(w1bT + ((size_t)((w * 4 + c) * 16 + kt) * 64 + lane) * 8);
#pragma unroll
            for (int rs = 0; rs < 4; ++rs)
                pacc[c][rs] = __builtin_amdgcn_mfma_f32_16x16x32_bf16(af, cf[rs], pacc[c][rs], 0, 0, 0);
        }
    }
    short4v cbr[4][4];
#pragma unroll
    for (int c = 0; c < 4; ++c) {
        f32x4 bv = *(const f32x4*)(b1 + (w * 4 + c) * 16 + quad * 4);
#pragma unroll
        for (int rs = 0; rs < 4; ++rs) {
            short4v o;
#pragma unroll
            for (int i = 0; i < 4; ++i) o[i] = f2bf(pacc[c][rs][i] + bv[i]);
            cbr[c][rs] = o;
        }
    }
    f32x4 b2r = *(const f32x4*)(b2 + jcol);  // b2 for this lane's 4 z-columns

    // ---- persistent weights into registers ----
    short8 wf1[4][4];
#pragma unroll
    for (int c = 0; c < 4; ++c)
#pragma unroll
        for (int kt = 0; kt < 4; ++kt)
            wf1[c][kt] = *(const short8*)(w1aT + ((size_t)((w * 4 + c) * 4 + kt) * 64 + lane) * 8);
    long wf2[16];
#pragma unroll
    for (int kt2 = 0; kt2 < 16; ++kt2)
        wf2[kt2] = w2T8[(size_t)(kt2 * 8 + w) * 64 + lane];

    // ---- init own z slice (u-layout: rows rs*16+m, cols jcol..jcol+4) ----
    float zr[4][4];
    float part = 0.f;
#pragma unroll
    for (int rs = 0; rs < 4; ++rs) {
        f32x4 e = *(const f32x4*)(eps0 + (size_t)(rowbase + rs * 16 + m) * NZ + jcol);
        short4v zb;
#pragma unroll
        for (int i = 0; i < 4; ++i) { zr[rs][i] = s0 * e[i]; zb[i] = f2bf(zr[rs][i]); }
        *(short4v*)(zu + rs * 4096 + zw_off) = zb;
    }
    __builtin_amdgcn_s_waitcnt(0xC07F);   // lgkmcnt(0)
    __builtin_amdgcn_s_barrier();          // initial: z published

#pragma unroll 1
    for (int t = 0; t < NT; ++t) {
        // eps prefetch — in flight through GEMM1, raw barrier B, and GEMM2
        f32x4 ef[4];
        {
            const float* ept = eps + (size_t)t * NB * NZ + (size_t)rowbase * NZ + jcol;
#pragma unroll
            for (int rs = 0; rs < 4; ++rs)
                ef[rs] = *(const f32x4*)(ept + (size_t)(rs * 16 + m) * NZ);
        }

        // ---- GEMM1 (bf16, weights in regs): 2 chunks of 2 h-tiles ----
#pragma unroll
        for (int cc = 0; cc < 2; ++cc) {
            f32x4 g1[2][4];
#pragma unroll
            for (int c2 = 0; c2 < 2; ++c2)
#pragma unroll
                for (int rs = 0; rs < 4; ++rs) g1[c2][rs] = zero;
#pragma unroll
            for (int kt = 0; kt < 4; ++kt) {
                short8 zb[4];
#pragma unroll
                for (int rs = 0; rs < 4; ++rs)
                    zb[rs] = *(const short8*)(zu + rs * 4096 + (zu_base ^ (kt << 6)));
#pragma unroll
                for (int c2 = 0; c2 < 2; ++c2)
#pragma unroll
                    for (int rs = 0; rs < 4; ++rs)
                        g1[c2][rs] = __builtin_amdgcn_mfma_f32_16x16x32_bf16(
                            wf1[cc * 2 + c2][kt], zb[rs], g1[c2][rs], 0, 0, 0);
            }
#pragma unroll
            for (int c2 = 0; c2 < 2; ++c2) {
                int c = cc * 2 + c2;
                // hid storage granule for h-tile ht=4w+c: paired-kt2 layout
                // g = (ht>>2)*4 + ((ht&1)<<1) + (quad>>1);  pr = (c>>1)&1
                int Gc = (((w * 4 + ((c & 1) << 1) + (quad >> 1)) ^ m) << 4)
                       + (((c >> 1) & 1) << 3);
                f32x4 te = *(const f32x4*)(t_emb + (size_t)t * NHID + (w * 4 + c) * 16 + quad * 4);
#pragma unroll
                for (int rs = 0; rs < 4; ++rs) {
                    float p0 = fmaxf(g1[c2][rs][0] + bf2f(cbr[c][rs][0]) + te[0], 0.f);
                    float p1 = fmaxf(g1[c2][rs][1] + bf2f(cbr[c][rs][1]) + te[1], 0.f);
                    float p2 = fmaxf(g1[c2][rs][2] + bf2f(cbr[c][rs][2]) + te[2], 0.f);
                    float p3 = fmaxf(g1[c2][rs][3] + bf2f(cbr[c][rs][3]) + te[3], 0.f);
                    int pk = __builtin_amdgcn_cvt_pk_fp8_f32(p0, p1, 0, false);
                    pk = __builtin_amdgcn_cvt_pk_fp8_f32(p2, p3, pk, true);
                    *(int*)(hidb + rs * 8192 + hw_base + Gc) = pk;
                }
            }
        }
        __builtin_amdgcn_s_waitcnt(0xC07F);   // lgkmcnt(0) — eps stays in flight
        __builtin_amdgcn_s_barrier();          // B: hid ready

        f32x4 sca = *(const f32x4*)(scb + t * 8);
        float c1mb = scb[t * 8 + 4];

        // ---- GEMM2 (fp8, weights in regs): j-tile jt=w, paired-kt2 b128 reads ----
        f32x4 ua[4];
#pragma unroll
        for (int rs = 0; rs < 4; ++rs) ua[rs] = zero;
#pragma unroll
        for (int kp = 0; kp < 8; ++kp) {
            long wlo = wf2[kp * 2];
            long whi = wf2[kp * 2 + 1];
            int go = ((kp * 4 + quad) ^ m) << 4;
#pragma unroll
            for (int rs = 0; rs < 4; ++rs) {
                long2v h2 = *(const long2v*)(hidb + rs * 8192 + hr_base + go);
                ua[rs] = __builtin_amdgcn_mfma_f32_16x16x32_fp8_fp8(wlo, h2[0], ua[rs], 0, 0, 0);
                ua[rs] = __builtin_amdgcn_mfma_f32_16x16x32_fp8_fp8(whi, h2[1], ua[rs], 0, 0, 0);
            }
        }

        // ---- elementwise, fully in registers (u = ua + b2) ----
#pragma unroll
        for (int rs = 0; rs < 4; ++rs) {
            short4v zb;
#pragma unroll
            for (int i = 0; i < 4; ++i) {
                float z = zr[rs][i];
                float e = ef[rs][i];
                float uu = ua[rs][i] + b2r[i];
                float mu_f = z + (sca[0] * z + uu) * dt;
                float zn = mu_f + sca[1] * e;
                float d = (z - zn * c1mb) * sca[2];
                part += -0.5f * d * d + 0.5f * e * e + sca[3];
                zr[rs][i] = zn;
                zb[i] = f2bf(zn);
            }
            *(short4v*)(zu + rs * 4096 + zw_off) = zb;
        }
        __builtin_amdgcn_s_waitcnt(0xC07F);   // lgkmcnt(0)
        __builtin_amdgcn_s_barrier();          // A: z published for next step
    }

    // ---- terminal + prior correction: (z0/s0) == eps0 exactly ----
#pragma unroll
    for (int rs = 0; rs < 4; ++rs) {
        const float* ep = eps0 + (size_t)(rowbase + rs * 16 + m) * NZ + jcol;
        const float* tp = target_mu + (size_t)(rowbase + rs * 16 + m) * NZ + jcol;
        f32x4 a = *(const f32x4*)ep;
        f32x4 ta = *(const f32x4*)tp;
#pragma unroll
        for (int i = 0; i < 4; ++i) {
            float d0 = zr[rs][i] - ta[i];
            part += -0.5f * d0 * d0 + 0.5f * a[i] * a[i] + logs0;
        }
    }
#pragma unroll
    for (int off = 32; off >= 1; off >>= 1) part += __shfl_xor(part, off, 64);
    if (lane == 0) atomicAdd(out, part * (1.0f / NB));
}

extern "C" void kernel_launch(void* const* d_in, const int* in_sizes, int n_in,
                              void* d_out, int out_size, void* d_ws, size_t ws_size,
                              hipStream_t stream) {
    const float* ctx  = (const float*)d_in[0];
    const float* eps0 = (const float*)d_in[1];
    const float* eps  = (const float*)d_in[2];
    const float* beta = (const float*)d_in[3];
    const float* sig0 = (const float*)d_in[4];
    const float* W1   = (const float*)d_in[5];
    const float* b1   = (const float*)d_in[6];
    const float* W2   = (const float*)d_in[7];
    const float* b2   = (const float*)d_in[8];
    const float* temb = (const float*)d_in[9];
    const float* tmu  = (const float*)d_in[10];
    float* out = (float*)d_out;

    char* ws = (char*)d_ws;
    short* w1aT = (short*)ws;                  // 131072 B
    long*  w2T8 = (long*)(ws + 131072);        //  65536 B (fp8 frags)
    short* w1bT = (short*)(ws + 196608);       // 524288 B

    hipMemsetAsync(d_out, 0, sizeof(float), stream);
    pack_weights<<<768, 64, 0, stream>>>(W1, W2, w1aT, w2T8, w1bT);
    diffusion_main<<<256, 512, 0, stream>>>(eps0, eps, beta, sig0, ctx, b1, b2,
                                            temb, tmu, w1aT, w1bT, w2T8, out);
}

// Round 4
// 536.035 us; speedup vs baseline: 1.2826x; 1.2826x over previous
//
#include <hip/hip_runtime.h>
#include <hip/hip_bf16.h>

#define NB 16384
#define NZ 128
#define NH 512
#define NHID 512
#define NT 32

typedef __attribute__((ext_vector_type(8))) short short8;
typedef __attribute__((ext_vector_type(4))) short short4v;
typedef __attribute__((ext_vector_type(4))) float f32x4;
typedef __attribute__((ext_vector_type(2))) long long2v;

__device__ __forceinline__ short f2bf(float x) {
    union { __hip_bfloat16 h; short s; } u; u.h = __float2bfloat16(x); return u.s;
}
__device__ __forceinline__ float bf2f(short s) {
    union { unsigned int u; float f; } v; v.u = ((unsigned int)(unsigned short)s) << 16; return v.f;
}

// ---------------------------------------------------------------------------
// Prologue pack:
//  w1aT  bf16 A-frags [ht(32)][kt(4)]   (128 frags x 1KB)
//  w2T8  fp8  A-frags [kt2(16)][jt(8)]  (128 frags x 512B)
//  w1bT  bf16 A-frags [ht(32)][kt(16)]  (512 frags x 1KB)
// A-frag 16x16x32: lane l holds A[m=l&15][k=(l>>4)*8+j], j=0..7.
// ---------------------------------------------------------------------------
__global__ __launch_bounds__(64) void pack_weights(const float* __restrict__ W1,
                                                   const float* __restrict__ W2,
                                                   short* __restrict__ w1aT,
                                                   long* __restrict__ w2T8,
                                                   short* __restrict__ w1bT) {
    int f = blockIdx.x;
    int l = threadIdx.x;
    int quad = l >> 4, m = l & 15;
    if (f < 128) {                       // W1a^T : A[h][k] = W1[k][h], k<128
        int ht = f >> 2, kt = f & 3;
        short8 o;
#pragma unroll
        for (int j = 0; j < 8; ++j)
            o[j] = f2bf(W1[(size_t)(kt * 32 + quad * 8 + j) * NH + ht * 16 + m]);
        *(short8*)(w1aT + ((size_t)f * 64 + l) * 8) = o;
    } else if (f < 256) {                // W2^T fp8 : A[j][k=h] = W2[h][j]
        int g = f - 128; int kt2 = g >> 3, jt = g & 7;
        float v[8];
#pragma unroll
        for (int j = 0; j < 8; ++j)
            v[j] = W2[(size_t)(kt2 * 32 + quad * 8 + j) * NZ + jt * 16 + m];
        int lo = __builtin_amdgcn_cvt_pk_fp8_f32(v[0], v[1], 0, false);
        lo = __builtin_amdgcn_cvt_pk_fp8_f32(v[2], v[3], lo, true);
        int hi = __builtin_amdgcn_cvt_pk_fp8_f32(v[4], v[5], 0, false);
        hi = __builtin_amdgcn_cvt_pk_fp8_f32(v[6], v[7], hi, true);
        long pv = ((long)(unsigned int)hi << 32) | (unsigned int)lo;
        w2T8[(size_t)g * 64 + l] = pv;
    } else {                             // W1b^T : A[h][k] = W1[128+k][h]
        int g = f - 256; int ht = g >> 4, kt = g & 15;
        short8 o;
#pragma unroll
        for (int j = 0; j < 8; ++j)
            o[j] = f2bf(W1[(size_t)(128 + kt * 32 + quad * 8 + j) * NH + ht * 16 + m]);
        *(short8*)(w1bT + ((size_t)g * 64 + l) * 8) = o;
    }
}

// ---------------------------------------------------------------------------
// Main: 256 blocks x 512 thr (8 waves), 64 rows/block. Round-0 structure
// (best measured: 294us main) + ONE graft: paired-kt2 hid layout (round-3
// verified) so GEMM2 does 32 ds_read_b128 near-conflict-free instead of
// 64 ds_read_b64 at 8-way conflict (measured -1.7e7 conflict cycles).
//
// REGISTER-CLIFF LAW (rounds 1/3 post-mortem): this kernel sits exactly at
// the 128-arch-VGPR limit. Do NOT extend liveness of anything across a GEMM
// phase (round 3: all-reg EW + early eps prefetch -> spills, FETCH +52MB,
// 1.4x slower). Do NOT use __launch_bounds__(512,4) (round 1: weights
// spill, 2.4x slower). Occupancy is pinned at 2 waves/SIMD by arch+acc
// pressure; grid games don't move it (round 2).
//
// Weights in REGISTERS for all 32 steps (wave w: W1a h-tiles [4w,4w+4) bf16
// = 64 VGPR; W2 jt=w fp8 = 32 VGPR). T-loop global loads: eps + t_emb only.
// LDS 49KB: zu[4][16][256B] bf16 (z and u, phase-disjoint) | hid[4][16][512B]
// fp8 paired-kt2 granules | sconst[32][8]f32.
// hid granule algebra (verified in round 3): 16B granule G=(4w+2(c&1)+
// (quad>>1))^m holds h-cols {64w+16c+4q..+3}; read side (kp,quad):
// G=(4kp+quad)^m gives kt2=2kp (lo 8B) and 2kp+1 (hi 8B) B-frags.
// Barriers: A,B = __syncthreads; C = raw s_barrier + lgkmcnt-only wait so the
// eps prefetch (issued at GEMM2 start) survives into the elementwise phase.
// ---------------------------------------------------------------------------
__global__ __launch_bounds__(512, 2) void diffusion_main(
    const float* __restrict__ eps0, const float* __restrict__ eps,
    const float* __restrict__ beta, const float* __restrict__ sigma0,
    const float* __restrict__ ctx, const float* __restrict__ b1,
    const float* __restrict__ b2, const float* __restrict__ t_emb,
    const float* __restrict__ target_mu,
    const short* __restrict__ w1aT, const short* __restrict__ w1bT,
    const long* __restrict__ w2T8, float* __restrict__ out)
{
    __shared__ alignas(16) char lds[50176];
    char* zu = lds;                      // 16 KB
    char* hidb = lds + 16384;            // 32 KB
    float* scb = (float*)(lds + 49152);  // 1 KB step constants
    const int w = threadIdx.x >> 6;
    const int lane = threadIdx.x & 63;
    const int quad = lane >> 4;
    const int m = lane & 15;
    const int swz = m & 7;
    const int rowbase = blockIdx.x * 64;
    const int ers = w >> 1;
    const int ek0 = (w & 1) << 1;
    const int erow = rowbase + ers * 16 + m;
    const float dt = 1.0f / 32.0f;
    const float s0 = sigma0[0];
    const float logs0 = logf(s0);
    const f32x4 zero = {0.f, 0.f, 0.f, 0.f};

    // XOR-swizzle address bases (per-lane constants)
    const int zu_base = m * 256 + ((quad ^ swz) << 4);                    // ^ (kt<<6), +rs*4096
    const int hw_base = m * 512 + ((quad & 1) << 2);                      // + Gc, +rs*8192
    const int hr_base = m * 512;                                          // +((4kp+quad)^m)<<4, +rs*8192
    const int ubw_off = m * 256 + ((((w << 1) + (quad >> 1)) ^ swz) << 4) + ((quad & 1) << 3);

    // step constants (computed once)
    if (threadIdx.x < 32) {
        int t = threadIdx.x;
        float bfv = beta[t];
        float bbv = beta[(t + 31) & 31];
        float sf = sqrtf(2.f * bfv * dt) * s0;
        float sb = sqrtf(2.f * bbv * dt) * s0;
        scb[t * 8 + 0] = bfv;
        scb[t * 8 + 1] = sf;
        scb[t * 8 + 2] = 1.f / sb;
        scb[t * 8 + 3] = 0.5f * (logf(bfv) - logf(bbv));
        scb[t * 8 + 4] = 1.f - bbv * dt;
    }

    // ---- prologue: cbr[c][rs] = (ctx @ W1b + b1), this wave's 4 h-tiles ----
    f32x4 pacc[4][4];
#pragma unroll
    for (int c = 0; c < 4; ++c)
#pragma unroll
        for (int rs = 0; rs < 4; ++rs) pacc[c][rs] = zero;
#pragma unroll 4
    for (int kt = 0; kt < 16; ++kt) {
        short8 cf[4];
#pragma unroll
        for (int rs = 0; rs < 4; ++rs) {
            const float* cp = ctx + (size_t)(rowbase + rs * 16 + m) * NH + kt * 32 + quad * 8;
            f32x4 a = *(const f32x4*)cp;
            f32x4 b = *(const f32x4*)(cp + 4);
            short8 tt;
#pragma unroll
            for (int j = 0; j < 4; ++j) { tt[j] = f2bf(a[j]); tt[4 + j] = f2bf(b[j]); }
            cf[rs] = tt;
        }
#pragma unroll
        for (int c = 0; c < 4; ++c) {
            short8 af = *(const short8*)(w1bT + ((size_t)((w * 4 + c) * 16 + kt) * 64 + lane) * 8);
#pragma unroll
            for (int rs = 0; rs < 4; ++rs)
                pacc[c][rs] = __builtin_amdgcn_mfma_f32_16x16x32_bf16(af, cf[rs], pacc[c][rs], 0, 0, 0);
        }
    }
    short4v cbr[4][4];
#pragma unroll
    for (int c = 0; c < 4; ++c) {
        f32x4 bv = *(const f32x4*)(b1 + (w * 4 + c) * 16 + quad * 4);
#pragma unroll
        for (int rs = 0; rs < 4; ++rs) {
            short4v o;
#pragma unroll
            for (int i = 0; i < 4; ++i) o[i] = f2bf(pacc[c][rs][i] + bv[i]);
            cbr[c][rs] = o;
        }
    }
    f32x4 b2r = *(const f32x4*)(b2 + w * 16 + quad * 4);

    // ---- persistent weights into registers ----
    short8 wf1[4][4];
#pragma unroll
    for (int c = 0; c < 4; ++c)
#pragma unroll
        for (int kt = 0; kt < 4; ++kt)
            wf1[c][kt] = *(const short8*)(w1aT + ((size_t)((w * 4 + c) * 4 + kt) * 64 + lane) * 8);
    long wf2[16];
#pragma unroll
    for (int kt2 = 0; kt2 < 16; ++kt2)
        wf2[kt2] = w2T8[(size_t)(kt2 * 8 + w) * 64 + lane];

    // ---- init own z slice, publish to zu ----
    float zr[2][8];
    float part = 0.f;
#pragma unroll
    for (int kk = 0; kk < 2; ++kk) {
        int kt = ek0 + kk;
        const float* ep = eps0 + (size_t)erow * NZ + kt * 32 + quad * 8;
        f32x4 a = *(const f32x4*)ep;
        f32x4 b = *(const f32x4*)(ep + 4);
        short8 zbw;
#pragma unroll
        for (int j = 0; j < 4; ++j) {
            zr[kk][j] = s0 * a[j]; zr[kk][4 + j] = s0 * b[j];
            zbw[j] = f2bf(zr[kk][j]); zbw[4 + j] = f2bf(zr[kk][4 + j]);
        }
        *(short8*)(zu + ers * 4096 + (zu_base ^ (kt << 6))) = zbw;
    }
    __syncthreads();   // A (initial)

#pragma unroll 1
    for (int t = 0; t < NT; ++t) {
        // ---- GEMM1 (bf16, weights in regs): 2 chunks of 2 h-tiles ----
#pragma unroll
        for (int cc = 0; cc < 2; ++cc) {
            f32x4 g1[2][4];
#pragma unroll
            for (int c2 = 0; c2 < 2; ++c2)
#pragma unroll
                for (int rs = 0; rs < 4; ++rs) g1[c2][rs] = zero;
#pragma unroll
            for (int kt = 0; kt < 4; ++kt) {
                short8 zb[4];
#pragma unroll
                for (int rs = 0; rs < 4; ++rs)
                    zb[rs] = *(const short8*)(zu + rs * 4096 + (zu_base ^ (kt << 6)));
#pragma unroll
                for (int c2 = 0; c2 < 2; ++c2)
#pragma unroll
                    for (int rs = 0; rs < 4; ++rs)
                        g1[c2][rs] = __builtin_amdgcn_mfma_f32_16x16x32_bf16(
                            wf1[cc * 2 + c2][kt], zb[rs], g1[c2][rs], 0, 0, 0);
            }
#pragma unroll
            for (int c2 = 0; c2 < 2; ++c2) {
                int c = cc * 2 + c2;
                // paired-kt2 granule address for h-tile ht=4w+c (round-3 verified)
                int Gc = (((w * 4 + ((c & 1) << 1) + (quad >> 1)) ^ m) << 4)
                       + (((c >> 1) & 1) << 3);
                f32x4 te = *(const f32x4*)(t_emb + (size_t)t * NHID + (w * 4 + c) * 16 + quad * 4);
#pragma unroll
                for (int rs = 0; rs < 4; ++rs) {
                    float p0 = fmaxf(g1[c2][rs][0] + bf2f(cbr[c][rs][0]) + te[0], 0.f);
                    float p1 = fmaxf(g1[c2][rs][1] + bf2f(cbr[c][rs][1]) + te[1], 0.f);
                    float p2 = fmaxf(g1[c2][rs][2] + bf2f(cbr[c][rs][2]) + te[2], 0.f);
                    float p3 = fmaxf(g1[c2][rs][3] + bf2f(cbr[c][rs][3]) + te[3], 0.f);
                    int pk = __builtin_amdgcn_cvt_pk_fp8_f32(p0, p1, 0, false);
                    pk = __builtin_amdgcn_cvt_pk_fp8_f32(p2, p3, pk, true);
                    *(int*)(hidb + rs * 8192 + hw_base + Gc) = pk;
                }
            }
        }
        __syncthreads();   // B: hid ready (nothing global in flight)

        // eps prefetch — stays in flight across raw barrier C
        f32x4 ef[2][2];
        {
            const float* ept = eps + (size_t)t * NB * NZ + (size_t)erow * NZ;
#pragma unroll
            for (int kk = 0; kk < 2; ++kk) {
                ef[kk][0] = *(const f32x4*)(ept + (ek0 + kk) * 32 + quad * 8);
                ef[kk][1] = *(const f32x4*)(ept + (ek0 + kk) * 32 + quad * 8 + 4);
            }
        }

        // ---- GEMM2 (fp8, weights in regs): j-tile jt=w, paired-kt2 b128 reads ----
        f32x4 ua[4];
#pragma unroll
        for (int rs = 0; rs < 4; ++rs) ua[rs] = zero;
#pragma unroll
        for (int kp = 0; kp < 8; ++kp) {
            long wlo = wf2[kp * 2];
            long whi = wf2[kp * 2 + 1];
            int go = ((kp * 4 + quad) ^ m) << 4;
#pragma unroll
            for (int rs = 0; rs < 4; ++rs) {
                long2v h2 = *(const long2v*)(hidb + rs * 8192 + hr_base + go);
                ua[rs] = __builtin_amdgcn_mfma_f32_16x16x32_fp8_fp8(wlo, h2[0], ua[rs], 0, 0, 0);
                ua[rs] = __builtin_amdgcn_mfma_f32_16x16x32_fp8_fp8(whi, h2[1], ua[rs], 0, 0, 0);
            }
        }
        // u (+b2) into zu region (z no longer needed there; lives in zr regs)
#pragma unroll
        for (int rs = 0; rs < 4; ++rs) {
            short4v o;
#pragma unroll
            for (int i = 0; i < 4; ++i) o[i] = f2bf(ua[rs][i] + b2r[i]);
            *(short4v*)(zu + rs * 4096 + ubw_off) = o;
        }
        __builtin_amdgcn_s_waitcnt(0xC07F);   // lgkmcnt(0) only — eps stays in flight
        __builtin_amdgcn_s_barrier();          // C: u ready

        // ---- elementwise: own rowset + kt-half ----
        f32x4 sca = *(const f32x4*)(scb + t * 8);
        float c1mb = scb[t * 8 + 4];
#pragma unroll
        for (int kk = 0; kk < 2; ++kk) {
            int kt = ek0 + kk;
            char* gaddr = zu + ers * 4096 + (zu_base ^ (kt << 6));
            short8 uv = *(const short8*)gaddr;
            float ee[8];
#pragma unroll
            for (int j = 0; j < 4; ++j) { ee[j] = ef[kk][0][j]; ee[4 + j] = ef[kk][1][j]; }
            short8 zbw;
#pragma unroll
            for (int j = 0; j < 8; ++j) {
                float z = zr[kk][j];
                float e = ee[j];
                float uu = bf2f(uv[j]);
                float mu_f = z + (sca[0] * z + uu) * dt;
                float zn = mu_f + sca[1] * e;
                float d = (z - zn * c1mb) * sca[2];
                part += -0.5f * d * d + 0.5f * e * e + sca[3];
                zr[kk][j] = zn;
                zbw[j] = f2bf(zn);
            }
            *(short8*)gaddr = zbw;
        }
        __syncthreads();   // A: z published for next step
    }

    // ---- terminal + prior correction: (z0/s0) == eps0 exactly ----
#pragma unroll
    for (int kk = 0; kk < 2; ++kk) {
        int kt = ek0 + kk;
        const float* ep = eps0 + (size_t)erow * NZ + kt * 32 + quad * 8;
        const float* tp = target_mu + (size_t)erow * NZ + kt * 32 + quad * 8;
        f32x4 a = *(const f32x4*)ep;
        f32x4 b = *(const f32x4*)(ep + 4);
        f32x4 ta = *(const f32x4*)tp;
        f32x4 tb = *(const f32x4*)(tp + 4);
#pragma unroll
        for (int j = 0; j < 4; ++j) {
            float d0 = zr[kk][j] - ta[j];
            float d1 = zr[kk][4 + j] - tb[j];
            part += -0.5f * d0 * d0 + 0.5f * a[j] * a[j] + logs0;
            part += -0.5f * d1 * d1 + 0.5f * b[j] * b[j] + logs0;
        }
    }
#pragma unroll
    for (int off = 32; off >= 1; off >>= 1) part += __shfl_xor(part, off, 64);
    if (lane == 0) atomicAdd(out, part * (1.0f / NB));
}

extern "C" void kernel_launch(void* const* d_in, const int* in_sizes, int n_in,
                              void* d_out, int out_size, void* d_ws, size_t ws_size,
                              hipStream_t stream) {
    const float* ctx  = (const float*)d_in[0];
    const float* eps0 = (const float*)d_in[1];
    const float* eps  = (const float*)d_in[2];
    const float* beta = (const float*)d_in[3];
    const float* sig0 = (const float*)d_in[4];
    const float* W1   = (const float*)d_in[5];
    const float* b1   = (const float*)d_in[6];
    const float* W2   = (const float*)d_in[7];
    const float* b2   = (const float*)d_in[8];
    const float* temb = (const float*)d_in[9];
    const float* tmu  = (const float*)d_in[10];
    float* out = (float*)d_out;

    char* ws = (char*)d_ws;
    short* w1aT = (short*)ws;                  // 131072 B
    long*  w2T8 = (long*)(ws + 131072);        //  65536 B (fp8 frags)
    short* w1bT = (short*)(ws + 196608);       // 524288 B

    hipMemsetAsync(d_out, 0, sizeof(float), stream);
    pack_weights<<<768, 64, 0, stream>>>(W1, W2, w1aT, w2T8, w1bT);
    diffusion_main<<<256, 512, 0, stream>>>(eps0, eps, beta, sig0, ctx, b1, b2,
                                            temb, tmu, w1aT, w1bT, w2T8, out);
}

// Round 5
// 529.531 us; speedup vs baseline: 1.2984x; 1.0123x over previous
//
#include <hip/hip_runtime.h>
#include <hip/hip_bf16.h>

#define NB 16384
#define NZ 128
#define NH 512
#define NHID 512
#define NT 32

typedef __attribute__((ext_vector_type(8))) short short8;
typedef __attribute__((ext_vector_type(4))) short short4v;
typedef __attribute__((ext_vector_type(4))) float f32x4;
typedef __attribute__((ext_vector_type(2))) long long2v;

__device__ __forceinline__ short f2bf(float x) {
    union { __hip_bfloat16 h; short s; } u; u.h = __float2bfloat16(x); return u.s;
}
__device__ __forceinline__ float bf2f(short s) {
    union { unsigned int u; float f; } v; v.u = ((unsigned int)(unsigned short)s) << 16; return v.f;
}

// ---------------------------------------------------------------------------
// Prologue pack:
//  w1aT  bf16 A-frags [ht(32)][kt(4)]   (128 frags x 1KB)
//  w2T8  fp8  A-frags [kt2(16)][jt(8)]  (128 frags x 512B)
//  w1bT  bf16 A-frags [ht(32)][kt(16)]  (512 frags x 1KB)
// A-frag 16x16x32: lane l holds A[m=l&15][k=(l>>4)*8+j], j=0..7.
// ---------------------------------------------------------------------------
__global__ __launch_bounds__(64) void pack_weights(const float* __restrict__ W1,
                                                   const float* __restrict__ W2,
                                                   short* __restrict__ w1aT,
                                                   long* __restrict__ w2T8,
                                                   short* __restrict__ w1bT) {
    int f = blockIdx.x;
    int l = threadIdx.x;
    int quad = l >> 4, m = l & 15;
    if (f < 128) {                       // W1a^T : A[h][k] = W1[k][h], k<128
        int ht = f >> 2, kt = f & 3;
        short8 o;
#pragma unroll
        for (int j = 0; j < 8; ++j)
            o[j] = f2bf(W1[(size_t)(kt * 32 + quad * 8 + j) * NH + ht * 16 + m]);
        *(short8*)(w1aT + ((size_t)f * 64 + l) * 8) = o;
    } else if (f < 256) {                // W2^T fp8 : A[j][k=h] = W2[h][j]
        int g = f - 128; int kt2 = g >> 3, jt = g & 7;
        float v[8];
#pragma unroll
        for (int j = 0; j < 8; ++j)
            v[j] = W2[(size_t)(kt2 * 32 + quad * 8 + j) * NZ + jt * 16 + m];
        int lo = __builtin_amdgcn_cvt_pk_fp8_f32(v[0], v[1], 0, false);
        lo = __builtin_amdgcn_cvt_pk_fp8_f32(v[2], v[3], lo, true);
        int hi = __builtin_amdgcn_cvt_pk_fp8_f32(v[4], v[5], 0, false);
        hi = __builtin_amdgcn_cvt_pk_fp8_f32(v[6], v[7], hi, true);
        long pv = ((long)(unsigned int)hi << 32) | (unsigned int)lo;
        w2T8[(size_t)g * 64 + l] = pv;
    } else {                             // W1b^T : A[h][k] = W1[128+k][h]
        int g = f - 256; int ht = g >> 4, kt = g & 15;
        short8 o;
#pragma unroll
        for (int j = 0; j < 8; ++j)
            o[j] = f2bf(W1[(size_t)(128 + kt * 32 + quad * 8 + j) * NH + ht * 16 + m]);
        *(short8*)(w1bT + ((size_t)g * 64 + l) * 8) = o;
    }
}

// ---------------------------------------------------------------------------
// Main: 256 blocks x 512 thr (8 waves), 64 rows/block. Round-4 base (253us,
// paired-kt2 hid layout) + two LDS/barrier cuts, both built from round-3
// HARNESS-VERIFIED algebra (round-3 passed; its regression was isolated to
// early-eps-prefetch liveness, NOT the layouts):
//  (1) GEMM1 chunked over rs-PAIRS (not c-pairs): each z-frag read ONCE
//      (16 b128/wave vs 32), g1[4][2]=32 regs (unchanged footprint).
//  (2) Elementwise consumes GEMM2's output registers directly (lane holds
//      u[rs*16+m][jcol+i], jcol=w*16+quad*4): barrier C + u round-trip
//      deleted (2 barriers/step). z re-published via the same zw_off
//      swizzle the old u-write used (write/read consistency verified).
//      eps prefetch STAYS at GEMM2 start (ef[4] liveness = round-4 window).
//
// REGISTER-CLIFF LAW (rounds 1/3): kernel sits at the 128-arch-VGPR limit.
// Do NOT extend liveness across a GEMM phase; do NOT use launch_bounds(,4).
// Occupancy pinned at 2 waves/SIMD by arch+acc pressure (round 2).
//
// LDS 49KB: zu[4][16][256B] bf16 z | hid[4][16][512B] fp8 paired-kt2 |
// sconst[32][8]f32. Spill guard: FETCH ~168.5MB, WRITE ~11.3MB.
// ---------------------------------------------------------------------------
__global__ __launch_bounds__(512, 2) void diffusion_main(
    const float* __restrict__ eps0, const float* __restrict__ eps,
    const float* __restrict__ beta, const float* __restrict__ sigma0,
    const float* __restrict__ ctx, const float* __restrict__ b1,
    const float* __restrict__ b2, const float* __restrict__ t_emb,
    const float* __restrict__ target_mu,
    const short* __restrict__ w1aT, const short* __restrict__ w1bT,
    const long* __restrict__ w2T8, float* __restrict__ out)
{
    __shared__ alignas(16) char lds[50176];
    char* zu = lds;                      // 16 KB
    char* hidb = lds + 16384;            // 32 KB
    float* scb = (float*)(lds + 49152);  // 1 KB step constants
    const int w = threadIdx.x >> 6;
    const int lane = threadIdx.x & 63;
    const int quad = lane >> 4;
    const int m = lane & 15;
    const int swz = m & 7;
    const int rowbase = blockIdx.x * 64;
    const int jcol = w * 16 + quad * 4;  // this lane's u/z columns (EW layout)
    const float dt = 1.0f / 32.0f;
    const float s0 = sigma0[0];
    const float logs0 = logf(s0);
    const f32x4 zero = {0.f, 0.f, 0.f, 0.f};

    // XOR-swizzle address bases (per-lane constants)
    const int zu_base = m * 256 + ((quad ^ swz) << 4);   // GEMM1 z read: ^ (kt<<6), +rs*4096
    const int hw_base = m * 512 + ((quad & 1) << 2);     // hid write: + Gc, +rs*8192
    const int hr_base = m * 512;                         // hid read: +((4kp+quad)^m)<<4, +rs*8192
    const int zw_off  = m * 256 + ((((w << 1) + (quad >> 1)) ^ swz) << 4)
                      + ((quad & 1) << 3);               // EW z write (u-layout), +rs*4096

    // step constants (computed once)
    if (threadIdx.x < 32) {
        int t = threadIdx.x;
        float bfv = beta[t];
        float bbv = beta[(t + 31) & 31];
        float sf = sqrtf(2.f * bfv * dt) * s0;
        float sb = sqrtf(2.f * bbv * dt) * s0;
        scb[t * 8 + 0] = bfv;
        scb[t * 8 + 1] = sf;
        scb[t * 8 + 2] = 1.f / sb;
        scb[t * 8 + 3] = 0.5f * (logf(bfv) - logf(bbv));
        scb[t * 8 + 4] = 1.f - bbv * dt;
    }

    // ---- prologue: cbr[c][rs] = (ctx @ W1b + b1), this wave's 4 h-tiles ----
    f32x4 pacc[4][4];
#pragma unroll
    for (int c = 0; c < 4; ++c)
#pragma unroll
        for (int rs = 0; rs < 4; ++rs) pacc[c][rs] = zero;
#pragma unroll 4
    for (int kt = 0; kt < 16; ++kt) {
        short8 cf[4];
#pragma unroll
        for (int rs = 0; rs < 4; ++rs) {
            const float* cp = ctx + (size_t)(rowbase + rs * 16 + m) * NH + kt * 32 + quad * 8;
            f32x4 a = *(const f32x4*)cp;
            f32x4 b = *(const f32x4*)(cp + 4);
            short8 tt;
#pragma unroll
            for (int j = 0; j < 4; ++j) { tt[j] = f2bf(a[j]); tt[4 + j] = f2bf(b[j]); }
            cf[rs] = tt;
        }
#pragma unroll
        for (int c = 0; c < 4; ++c) {
            short8 af = *(const short8*)(w1bT + ((size_t)((w * 4 + c) * 16 + kt) * 64 + lane) * 8);
#pragma unroll
            for (int rs = 0; rs < 4; ++rs)
                pacc[c][rs] = __builtin_amdgcn_mfma_f32_16x16x32_bf16(af, cf[rs], pacc[c][rs], 0, 0, 0);
        }
    }
    short4v cbr[4][4];
#pragma unroll
    for (int c = 0; c < 4; ++c) {
        f32x4 bv = *(const f32x4*)(b1 + (w * 4 + c) * 16 + quad * 4);
#pragma unroll
        for (int rs = 0; rs < 4; ++rs) {
            short4v o;
#pragma unroll
            for (int i = 0; i < 4; ++i) o[i] = f2bf(pacc[c][rs][i] + bv[i]);
            cbr[c][rs] = o;
        }
    }
    f32x4 b2r = *(const f32x4*)(b2 + jcol);  // b2 for this lane's EW columns

    // ---- persistent weights into registers ----
    short8 wf1[4][4];
#pragma unroll
    for (int c = 0; c < 4; ++c)
#pragma unroll
        for (int kt = 0; kt < 4; ++kt)
            wf1[c][kt] = *(const short8*)(w1aT + ((size_t)((w * 4 + c) * 4 + kt) * 64 + lane) * 8);
    long wf2[16];
#pragma unroll
    for (int kt2 = 0; kt2 < 16; ++kt2)
        wf2[kt2] = w2T8[(size_t)(kt2 * 8 + w) * 64 + lane];

    // ---- init own z slice (u-layout: rows rs*16+m, cols jcol..jcol+3) ----
    float zr[4][4];
    float part = 0.f;
#pragma unroll
    for (int rs = 0; rs < 4; ++rs) {
        f32x4 e = *(const f32x4*)(eps0 + (size_t)(rowbase + rs * 16 + m) * NZ + jcol);
        short4v zb;
#pragma unroll
        for (int i = 0; i < 4; ++i) { zr[rs][i] = s0 * e[i]; zb[i] = f2bf(zr[rs][i]); }
        *(short4v*)(zu + rs * 4096 + zw_off) = zb;
    }
    __syncthreads();   // A (initial)

#pragma unroll 1
    for (int t = 0; t < NT; ++t) {
        // ---- GEMM1 (bf16, weights in regs): 2 chunks of 2 ROWSETS ----
        // Each z-frag read exactly once; 4:1 MFMA:LDS-read ratio.
#pragma unroll
        for (int rr = 0; rr < 2; ++rr) {
            f32x4 g1[4][2];
#pragma unroll
            for (int c = 0; c < 4; ++c)
#pragma unroll
                for (int r2 = 0; r2 < 2; ++r2) g1[c][r2] = zero;
#pragma unroll
            for (int kt = 0; kt < 4; ++kt) {
                short8 zb[2];
#pragma unroll
                for (int r2 = 0; r2 < 2; ++r2)
                    zb[r2] = *(const short8*)(zu + (rr * 2 + r2) * 4096 + (zu_base ^ (kt << 6)));
#pragma unroll
                for (int c = 0; c < 4; ++c)
#pragma unroll
                    for (int r2 = 0; r2 < 2; ++r2)
                        g1[c][r2] = __builtin_amdgcn_mfma_f32_16x16x32_bf16(
                            wf1[c][kt], zb[r2], g1[c][r2], 0, 0, 0);
            }
#pragma unroll
            for (int c = 0; c < 4; ++c) {
                // paired-kt2 granule address for h-tile ht=4w+c (round-3/4 verified)
                int Gc = (((w * 4 + ((c & 1) << 1) + (quad >> 1)) ^ m) << 4)
                       + (((c >> 1) & 1) << 3);
                f32x4 te = *(const f32x4*)(t_emb + (size_t)t * NHID + (w * 4 + c) * 16 + quad * 4);
#pragma unroll
                for (int r2 = 0; r2 < 2; ++r2) {
                    int rs = rr * 2 + r2;
                    float p0 = fmaxf(g1[c][r2][0] + bf2f(cbr[c][rs][0]) + te[0], 0.f);
                    float p1 = fmaxf(g1[c][r2][1] + bf2f(cbr[c][rs][1]) + te[1], 0.f);
                    float p2 = fmaxf(g1[c][r2][2] + bf2f(cbr[c][rs][2]) + te[2], 0.f);
                    float p3 = fmaxf(g1[c][r2][3] + bf2f(cbr[c][rs][3]) + te[3], 0.f);
                    int pk = __builtin_amdgcn_cvt_pk_fp8_f32(p0, p1, 0, false);
                    pk = __builtin_amdgcn_cvt_pk_fp8_f32(p2, p3, pk, true);
                    *(int*)(hidb + rs * 8192 + hw_base + Gc) = pk;
                }
            }
        }
        __syncthreads();   // B: hid ready

        // eps prefetch (u-layout rows) — latency hides under GEMM2
        f32x4 ef[4];
        {
            const float* ept = eps + (size_t)t * NB * NZ + (size_t)rowbase * NZ + jcol;
#pragma unroll
            for (int rs = 0; rs < 4; ++rs)
                ef[rs] = *(const f32x4*)(ept + (size_t)(rs * 16 + m) * NZ);
        }
        f32x4 sca = *(const f32x4*)(scb + t * 8);
        float c1mb = scb[t * 8 + 4];

        // ---- GEMM2 (fp8, weights in regs): j-tile jt=w, paired-kt2 b128 reads ----
        f32x4 ua[4];
#pragma unroll
        for (int rs = 0; rs < 4; ++rs) ua[rs] = zero;
#pragma unroll
        for (int kp = 0; kp < 8; ++kp) {
            long wlo = wf2[kp * 2];
            long whi = wf2[kp * 2 + 1];
            int go = ((kp * 4 + quad) ^ m) << 4;
#pragma unroll
            for (int rs = 0; rs < 4; ++rs) {
                long2v h2 = *(const long2v*)(hidb + rs * 8192 + hr_base + go);
                ua[rs] = __builtin_amdgcn_mfma_f32_16x16x32_fp8_fp8(wlo, h2[0], ua[rs], 0, 0, 0);
                ua[rs] = __builtin_amdgcn_mfma_f32_16x16x32_fp8_fp8(whi, h2[1], ua[rs], 0, 0, 0);
            }
        }

        // ---- elementwise, fully in registers (u = ua + b2); no barrier C ----
#pragma unroll
        for (int rs = 0; rs < 4; ++rs) {
            short4v zb;
#pragma unroll
            for (int i = 0; i < 4; ++i) {
                float z = zr[rs][i];
                float e = ef[rs][i];
                float uu = ua[rs][i] + b2r[i];
                float mu_f = z + (sca[0] * z + uu) * dt;
                float zn = mu_f + sca[1] * e;
                float d = (z - zn * c1mb) * sca[2];
                part += -0.5f * d * d + 0.5f * e * e + sca[3];
                zr[rs][i] = zn;
                zb[i] = f2bf(zn);
            }
            *(short4v*)(zu + rs * 4096 + zw_off) = zb;
        }
        __syncthreads();   // A: z published for next step
    }

    // ---- terminal + prior correction: (z0/s0) == eps0 exactly ----
#pragma unroll
    for (int rs = 0; rs < 4; ++rs) {
        const float* ep = eps0 + (size_t)(rowbase + rs * 16 + m) * NZ + jcol;
        const float* tp = target_mu + (size_t)(rowbase + rs * 16 + m) * NZ + jcol;
        f32x4 a = *(const f32x4*)ep;
        f32x4 ta = *(const f32x4*)tp;
#pragma unroll
        for (int i = 0; i < 4; ++i) {
            float d0 = zr[rs][i] - ta[i];
            part += -0.5f * d0 * d0 + 0.5f * a[i] * a[i] + logs0;
        }
    }
#pragma unroll
    for (int off = 32; off >= 1; off >>= 1) part += __shfl_xor(part, off, 64);
    if (lane == 0) atomicAdd(out, part * (1.0f / NB));
}

extern "C" void kernel_launch(void* const* d_in, const int* in_sizes, int n_in,
                              void* d_out, int out_size, void* d_ws, size_t ws_size,
                              hipStream_t stream) {
    const float* ctx  = (const float*)d_in[0];
    const float* eps0 = (const float*)d_in[1];
    const float* eps  = (const float*)d_in[2];
    const float* beta = (const float*)d_in[3];
    const float* sig0 = (const float*)d_in[4];
    const float* W1   = (const float*)d_in[5];
    const float* b1   = (const float*)d_in[6];
    const float* W2   = (const float*)d_in[7];
    const float* b2   = (const float*)d_in[8];
    const float* temb = (const float*)d_in[9];
    const float* tmu  = (const float*)d_in[10];
    float* out = (float*)d_out;

    char* ws = (char*)d_ws;
    short* w1aT = (short*)ws;                  // 131072 B
    long*  w2T8 = (long*)(ws + 131072);        //  65536 B (fp8 frags)
    short* w1bT = (short*)(ws + 196608);       // 524288 B

    hipMemsetAsync(d_out, 0, sizeof(float), stream);
    pack_weights<<<768, 64, 0, stream>>>(W1, W2, w1aT, w2T8, w1bT);
    diffusion_main<<<256, 512, 0, stream>>>(eps0, eps, beta, sig0, ctx, b1, b2,
                                            temb, tmu, w1aT, w1bT, w2T8, out);
}